// Round 13
// baseline (111.373 us; speedup 1.0000x reference)
//
#include <hip/hip_runtime.h>
#include <math.h>

#define HW 16384
#define Wd 128

typedef __attribute__((ext_vector_type(8))) short short8;
typedef __attribute__((ext_vector_type(4))) float f32x4;

__device__ __forceinline__ unsigned cvt_pk_bf16(float a, float b) {
  unsigned r;                                   // r = bf16(a) | bf16(b)<<16
  asm("v_cvt_pk_bf16_f32 %0, %1, %2" : "=v"(r) : "v"(a), "v"(b));
  return r;
}

__device__ __forceinline__ unsigned short bf16r(float f) {
  unsigned int u = __float_as_uint(f);
  unsigned int r = (u + 0x7FFFu + ((u >> 16) & 1u)) >> 16;   // RNE
  return (unsigned short)r;
}

// ---------------- K1: per (b,c) spatial mean ----------------
__global__ void k_mean(const float* __restrict__ x, float* __restrict__ xmean) {
  int bc = blockIdx.x;                       // 0..95  (b*48+c)
  const float* p = x + (size_t)bc * HW;
  float s = 0.f;
  for (int i = threadIdx.x; i < HW; i += 256) s += p[i];
  #pragma unroll
  for (int off = 32; off > 0; off >>= 1) s += __shfl_down(s, off, 64);
  __shared__ float wsum[4];
  int lane = threadIdx.x & 63, wv = threadIdx.x >> 6;
  if (lane == 0) wsum[wv] = s;
  __syncthreads();
  if (threadIdx.x == 0)
    xmean[bc] = (wsum[0] + wsum[1] + wsum[2] + wsum[3]) * (1.f / 16384.f);
}

__global__ void k_sca(const float* __restrict__ xmean, const float* __restrict__ w_sca,
                      const float* __restrict__ b_sca, float* __restrict__ sca) {
  int t = threadIdx.x;
  if (t < 192) {
    int b = t / 96, co = t % 96;
    float acc = b_sca[co];
    for (int ci = 0; ci < 48; ci++) acc += w_sca[co * 48 + ci] * xmean[b * 48 + ci];
    sca[t] = acc;
  }
}

// ---------------- K3: two 1x1 convs 48->96 + w211 1x1 (a2 of att) ----------------
// grid (512,8): 64 px per block; slot (0..31) handles 3 h-channels + 1 att channel
__global__ void k_pw1(const float* __restrict__ x,
                      const float* __restrict__ w1a, const float* __restrict__ b1a,
                      const float* __restrict__ w1c, const float* __restrict__ b1c,
                      const float* __restrict__ w211, const float* __restrict__ b211,
                      float* __restrict__ ha, float* __restrict__ hc,
                      float* __restrict__ att) {
  int lane = threadIdx.x & 63;
  int wv = __builtin_amdgcn_readfirstlane((int)(threadIdx.x >> 6));
  int slot = __builtin_amdgcn_readfirstlane((int)(blockIdx.y * 4 + wv));
  int p = blockIdx.x * 64 + lane;
  int b = p >> 14, sp = p & (HW - 1);
  const float* xb = x + (size_t)b * 48 * HW + sp;
  float xv[48];
  #pragma unroll
  for (int ci = 0; ci < 48; ci++) xv[ci] = xb[(size_t)ci * HW];
  float* hab = ha + (size_t)b * 96 * HW + sp;
  float* hcb = hc + (size_t)b * 96 * HW + sp;
  int c0 = slot * 3;
  for (int co = c0; co < c0 + 3; co++) {
    float aa = b1a[co], ac = b1c[co];
    const float* wa = w1a + co * 48;
    const float* wc = w1c + co * 48;
    #pragma unroll
    for (int ci = 0; ci < 48; ci++) { aa += wa[ci] * xv[ci]; ac += wc[ci] * xv[ci]; }
    hab[(size_t)co * HW] = aa;
    hcb[(size_t)co * HW] = ac;
  }
  // a2 part of att: att[n] = b211[n] + w211[n]·x  (a1*gamma added in k_att2)
  {
    int n = slot;
    float a2 = b211[n];
    const float* w2 = w211 + n * 48;
    #pragma unroll
    for (int ci = 0; ci < 48; ci++) a2 += w2[ci] * xv[ci];
    att[(size_t)b * 32 * HW + (size_t)n * HW + sp] = a2;
  }
}

// ---------------- K4: depthwise 3x3; x1 path gets gelu*sca folded in ----------------
__global__ void k_dw(const float* __restrict__ ha, const float* __restrict__ hc,
                     const float* __restrict__ wdwa, const float* __restrict__ bdwa,
                     const float* __restrict__ wdwc, const float* __restrict__ bdwc,
                     const float* __restrict__ sca,
                     float* __restrict__ x1g, float* __restrict__ uf) {
  int idx = blockIdx.x * 256 + threadIdx.x;        // < B*96*HW
  int sp = idx & (HW - 1);
  int bc = idx >> 14;                              // b*96+ch
  int ch = bc % 96;
  int r = sp >> 7, c = sp & 127;
  const float* pa = ha + (size_t)bc * HW;
  const float* pc = hc + (size_t)bc * HW;
  float aa = bdwa[ch], ac = bdwc[ch];
  #pragma unroll
  for (int t9 = 0; t9 < 9; t9++) {
    int rr = r + t9 / 3 - 1, cc = c + t9 % 3 - 1;
    bool ok = ((unsigned)rr < 128u) && ((unsigned)cc < 128u);
    float va = ok ? pa[rr * Wd + cc] : 0.f;
    float vc = ok ? pc[rr * Wd + cc] : 0.f;
    aa += wdwa[ch * 9 + t9] * va;
    ac += wdwc[ch * 9 + t9] * vc;
  }
  float gl = aa * 0.5f * (1.f + erff(aa * 0.70710678118654752440f));
  x1g[idx] = gl * sca[bc];
  uf[idx] = ac;
}

// ---------------- K5a: gate m = t1*t2 (grouped 3x3 + SimpleGate) ----------------
__global__ void k_gate(const float* __restrict__ x, const float* __restrict__ wc2a,
                       const float* __restrict__ bc2a, float* __restrict__ m) {
  int idx = blockIdx.x * 256 + threadIdx.x;        // < B*12*HW = 393216
  int sp = idx & (HW - 1);
  int bi = idx >> 14;                              // b*12+i
  int i = bi % 12, b = bi / 12;
  int r = sp >> 7, c = sp & 127;
  const float* xb = x + (size_t)b * 48 * HW;
  float t[2];
  #pragma unroll
  for (int half = 0; half < 2; half++) {
    int o = i + half * 12;
    float acc = bc2a[o];
    #pragma unroll
    for (int ic = 0; ic < 2; ic++) {
      const float* xc = xb + (size_t)(2 * o + ic) * HW;
      const float* wo = wc2a + o * 18 + ic * 9;
      #pragma unroll
      for (int t9 = 0; t9 < 9; t9++) {
        int rr = r + t9 / 3 - 1, cc = c + t9 % 3 - 1;
        float v = (((unsigned)rr < 128u) && ((unsigned)cc < 128u)) ? xc[rr * Wd + cc] : 0.f;
        acc += wo[t9] * v;
      }
    }
    t[half] = acc;
  }
  m[idx] = t[0] * t[1];
}

// ---------------- K5b: att += 1x1(m)*gamma, IN PLACE (a2 already there) ----------
// grid (512,4): slot (0..15) handles 2 att channels; 1:1 thread<->addr, no race
__global__ void k_att2(const float* __restrict__ m,
                       const float* __restrict__ wc2b, const float* __restrict__ bc2b,
                       const float* __restrict__ attg, float* __restrict__ att) {
  int lane = threadIdx.x & 63;
  int wv = __builtin_amdgcn_readfirstlane((int)(threadIdx.x >> 6));
  int slot = __builtin_amdgcn_readfirstlane((int)(blockIdx.y * 4 + wv));
  int p = blockIdx.x * 64 + lane;
  int b = p >> 14, sp = p & (HW - 1);
  float mv[12];
  const float* mb = m + (size_t)b * 12 * HW + sp;
  #pragma unroll
  for (int i = 0; i < 12; i++) mv[i] = mb[(size_t)i * HW];
  float* ab = att + (size_t)b * 32 * HW + sp;
  int n0 = slot * 2;
  for (int n = n0; n < n0 + 2; n++) {
    float a1 = bc2b[n];
    #pragma unroll
    for (int i = 0; i < 12; i++) a1 += wc2b[n * 12 + i] * mv[i];
    float* ap = ab + (size_t)n * HW;
    *ap = a1 * attg[n] + *ap;
  }
}

// ---------------- K_prep: kbw+kbb -> bf16 A-tile [48][64][32]; + wproj hi/lo -----
// blocks 0..383: kwA. blocks 384..401: wp (wproj hi + lo residual).
// K-slot map (center-aligned; q = k>>3, j2 = k&7):
//   q0: j2<5 -> jj = j2 ; q1: j2<5 -> jj = 9+j2 ; q2: j2<4 -> jj = 5+j2 ;
//   q3: j2<4 -> jj = 14+j2, j2==4 -> bias
__global__ void k_prep(const float* __restrict__ kbw, const float* __restrict__ kbb,
                       const float* __restrict__ wproj,
                       unsigned short* __restrict__ kwA, unsigned short* __restrict__ wp) {
  int blk = blockIdx.x;
  if (blk < 384) {
    int e = blk * 256 + threadIdx.x;               // < 98304
    int k = e & 31, nc = (e >> 5) & 63, g = e >> 11;
    int n = nc >> 1, i = nc & 1;
    int q = k >> 3, j2 = k & 7;
    float v = 0.f;
    int jj = -1;
    if (q == 0)      { if (j2 < 5) jj = j2; }
    else if (q == 1) { if (j2 < 5) jj = 9 + j2; }
    else if (q == 2) { if (j2 < 4) jj = 5 + j2; }
    else             { if (j2 < 4) jj = 14 + j2; else if (j2 == 4) v = kbb[n * 96 + 2 * g + i]; }
    if (jj >= 0) v = kbw[n * 1728 + g * 36 + i * 18 + jj];
    kwA[e] = bf16r(v);
  } else {
    int e = (blk - 384) * 256 + threadIdx.x;       // < 4608
    if (e < 4608) {
      float w = wproj[e];
      unsigned short h = bf16r(w);
      wp[e] = h;
      float hif = __uint_as_float((unsigned)h << 16);
      wp[4608 + e] = bf16r(w - hif);
    }
  }
}

// ---------------- K6: fused kba via MFMA ----------------
// grid (512,24) x 256. Wave wv owns px [wv*16,+16); block covers 2 groups gq*2..+1.
// kwA staged in LDS (8 KB); all loop global reads (10 taps, 4 x1g, 8 att)
// prefetched in the preamble. y2: packed bf16 ch-pairs (u32 = even | odd<<16).
__global__ __launch_bounds__(256) void k_kba(
    const float* __restrict__ uf, const float* __restrict__ x1g,
    const float* __restrict__ att, const unsigned short* __restrict__ kwA,
    const float* __restrict__ ga1, unsigned int* __restrict__ y2) {
  __shared__ __align__(16) short kwS[2 * 2048];    // 8 KB
  int tid = threadIdx.x;
  int lane = tid & 63;
  int wv = tid >> 6;
  int lo = lane & 15, hi = lane >> 4;
  int bid = blockIdx.x;                            // 0..511
  int b = bid >> 8;
  int sp = ((bid & 255) << 6) + wv * 16 + lo;      // this lane's pixel
  int r = sp >> 7, c = sp & 127;
  int g0 = blockIdx.y * 2;

  // stage this block's 2 groups of kwA into LDS (coalesced 16B copies)
  {
    const short8* src = (const short8*)(kwA + g0 * 2048);
    short8* dst = (short8*)kwS;
    #pragma unroll
    for (int i = 0; i < 2; i++) dst[tid + 256 * i] = src[tid + 256 * i];
  }

  const float* ufb  = uf  + (size_t)b * 96 * HW;
  const float* x1gb = x1g + (size_t)b * 96 * HW;
  const float* attb = att + (size_t)b * 32 * HW;
  unsigned int* y2b = y2 + (size_t)b * 48 * HW;

  float attv[8];
  #pragma unroll
  for (int mt = 0; mt < 4; mt++)
    #pragma unroll
    for (int q = 0; q < 2; q++)
      attv[mt * 2 + q] = attb[(size_t)(8 * mt + 2 * hi + q) * HW + sp];

  const float* pj[5];
  bool ok[5];
  float dv[5];
  #pragma unroll
  for (int j2 = 0; j2 < 5; j2++) {
    int jj = (hi == 0) ? j2 : (hi == 1) ? 9 + j2 : (hi == 2) ? 5 + j2 : 14 + j2;
    bool real = (hi < 2) || (j2 < 4);
    if (real) {
      int ch = jj / 9, tap = jj % 9;
      int rr = r + tap / 3 - 1, cc = c + tap % 3 - 1;
      bool inb = ((unsigned)rr < 128u) && ((unsigned)cc < 128u);
      ok[j2] = inb;
      dv[j2] = 0.f;
      pj[j2] = ufb + (size_t)(2 * g0 + ch) * HW + (inb ? rr * Wd + cc : 0);
    } else {
      ok[j2] = false;
      dv[j2] = (hi == 3) ? 1.f : 0.f;              // bias slot (q3, j2==4)
      pj[j2] = ufb;
    }
  }

  // prefetch both groups' taps (10 loads) and the 4 x1g values
  float va[5], vb[5];
  #pragma unroll
  for (int j2 = 0; j2 < 5; j2++) va[j2] = ok[j2] ? pj[j2][0]      : dv[j2];
  #pragma unroll
  for (int j2 = 0; j2 < 5; j2++) vb[j2] = ok[j2] ? pj[j2][2 * HW] : dv[j2];
  float x1v[4];
  #pragma unroll
  for (int k = 0; k < 4; k++)
    x1v[k] = x1gb[(size_t)(2 * g0 + k) * HW + sp];

  __syncthreads();                                 // staging complete

  const short* kgA = kwS;
  const short* kgB = kwS + 2048;
  short8 afrA[4], afrB[4];
  #pragma unroll
  for (int mt = 0; mt < 4; mt++) {
    afrA[mt] = *(const short8*)(kgA + (16 * mt + lo) * 32 + hi * 8);
    afrB[mt] = *(const short8*)(kgB + (16 * mt + lo) * 32 + hi * 8);
  }
  union { unsigned u[4]; short8 s; } bfA, bfB;
  bfA.u[0] = cvt_pk_bf16(va[0], va[1]);
  bfA.u[1] = cvt_pk_bf16(va[2], va[3]);
  bfA.u[2] = cvt_pk_bf16(va[4], 0.f);
  bfA.u[3] = 0u;
  bfB.u[0] = cvt_pk_bf16(vb[0], vb[1]);
  bfB.u[1] = cvt_pk_bf16(vb[2], vb[3]);
  bfB.u[2] = cvt_pk_bf16(vb[4], 0.f);
  bfB.u[3] = 0u;
  f32x4 accA[4], accB[4];
  f32x4 zero = {0.f, 0.f, 0.f, 0.f};
  #pragma unroll
  for (int mt = 0; mt < 4; mt++)
    accA[mt] = __builtin_amdgcn_mfma_f32_16x16x32_bf16(afrA[mt], bfA.s, zero, 0, 0, 0);
  #pragma unroll
  for (int mt = 0; mt < 4; mt++)
    accB[mt] = __builtin_amdgcn_mfma_f32_16x16x32_bf16(afrB[mt], bfB.s, zero, 0, 0, 0);
  float sA0 = 0.f, sA1 = 0.f, sB0 = 0.f, sB1 = 0.f;
  #pragma unroll
  for (int mt = 0; mt < 4; mt++) {
    sA0 += attv[mt * 2 + 0] * accA[mt][0] + attv[mt * 2 + 1] * accA[mt][2];
    sA1 += attv[mt * 2 + 0] * accA[mt][1] + attv[mt * 2 + 1] * accA[mt][3];
  }
  sA0 += __shfl_xor(sA0, 16); sA0 += __shfl_xor(sA0, 32);
  sA1 += __shfl_xor(sA1, 16); sA1 += __shfl_xor(sA1, 32);
  float cenA = __shfl_xor(va[4], 16);
  #pragma unroll
  for (int mt = 0; mt < 4; mt++) {
    sB0 += attv[mt * 2 + 0] * accB[mt][0] + attv[mt * 2 + 1] * accB[mt][2];
    sB1 += attv[mt * 2 + 0] * accB[mt][1] + attv[mt * 2 + 1] * accB[mt][3];
  }
  sB0 += __shfl_xor(sB0, 16); sB0 += __shfl_xor(sB0, 32);
  sB1 += __shfl_xor(sB1, 16); sB1 += __shfl_xor(sB1, 32);
  float cenB = __shfl_xor(vb[4], 16);
  if (hi == 0) {
    int c0 = 2 * g0;
    float xa0 = sA0 * ga1[c0]     + va[4];
    float xa1 = sA1 * ga1[c0 + 1] + cenA;
    float ya0 = x1v[0] * xa0;
    float ya1 = x1v[1] * xa1;
    y2b[(size_t)g0 * HW + sp] = cvt_pk_bf16(ya0, ya1);
    float xb0 = sB0 * ga1[c0 + 2] + vb[4];
    float xb1 = sB1 * ga1[c0 + 3] + cenB;
    float yb0 = x1v[2] * xb0;
    float yb1 = x1v[3] * xb1;
    y2b[(size_t)(g0 + 1) * HW + sp] = cvt_pk_bf16(yb0, yb1);
  }
}

// ---------------- K7: project_out 96->48 via MFMA (W = bf16 hi + bf16 lo) -------
// grid 512 x 256. Wave handles 16 px, all 48 out-channels (3 row-tiles).
__global__ void k_proj(const unsigned int* __restrict__ y2, const unsigned short* __restrict__ wp,
                       const float* __restrict__ bproj, float* __restrict__ out) {
  int tid = threadIdx.x;
  int lane = tid & 63;
  int wv = tid >> 6;
  int lo = lane & 15, hi = lane >> 4;
  int p0 = blockIdx.x * 64 + wv * 16;
  int b = p0 >> 14;
  int sp = (p0 & (HW - 1)) + lo;
  const unsigned int* yb = y2 + (size_t)b * 48 * HW + sp;
  union { unsigned u[4]; short8 s; } bf[3];
  #pragma unroll
  for (int ks = 0; ks < 3; ks++)
    #pragma unroll
    for (int q = 0; q < 4; q++)
      bf[ks].u[q] = yb[(size_t)(ks * 16 + hi * 4 + q) * HW];
  f32x4 acc[3];
  #pragma unroll
  for (int t = 0; t < 3; t++)
    #pragma unroll
    for (int r = 0; r < 4; r++)
      acc[t][r] = bproj[16 * t + 4 * hi + r];
  #pragma unroll
  for (int t = 0; t < 3; t++) {
    #pragma unroll
    for (int ks = 0; ks < 3; ks++) {
      short8 ah = *(const short8*)(wp + (16 * t + lo) * 96 + ks * 32 + hi * 8);
      acc[t] = __builtin_amdgcn_mfma_f32_16x16x32_bf16(ah, bf[ks].s, acc[t], 0, 0, 0);
      short8 al = *(const short8*)(wp + 4608 + (16 * t + lo) * 96 + ks * 32 + hi * 8);
      acc[t] = __builtin_amdgcn_mfma_f32_16x16x32_bf16(al, bf[ks].s, acc[t], 0, 0, 0);
    }
  }
  float* ob = out + (size_t)b * 48 * HW + sp;
  #pragma unroll
  for (int t = 0; t < 3; t++)
    #pragma unroll
    for (int r = 0; r < 4; r++)
      ob[(size_t)(16 * t + 4 * hi + r) * HW] = acc[t][r];
}

extern "C" void kernel_launch(void* const* d_in, const int* in_sizes, int n_in,
                              void* d_out, int out_size, void* d_ws, size_t ws_size,
                              hipStream_t stream) {
  const float* x    = (const float*)d_in[0];
  const float* w1a  = (const float*)d_in[1];
  const float* b1a  = (const float*)d_in[2];
  const float* wdwa = (const float*)d_in[3];
  const float* bdwa = (const float*)d_in[4];
  const float* w1c  = (const float*)d_in[5];
  const float* b1c  = (const float*)d_in[6];
  const float* wdwc = (const float*)d_in[7];
  const float* bdwc = (const float*)d_in[8];
  const float* wsca = (const float*)d_in[9];
  const float* bsca = (const float*)d_in[10];
  const float* wc2a = (const float*)d_in[11];
  const float* bc2a = (const float*)d_in[12];
  const float* wc2b = (const float*)d_in[13];
  const float* bc2b = (const float*)d_in[14];
  const float* w211 = (const float*)d_in[15];
  const float* b211 = (const float*)d_in[16];
  const float* wproj= (const float*)d_in[17];
  const float* bproj= (const float*)d_in[18];
  const float* kbw  = (const float*)d_in[19];
  const float* kbb  = (const float*)d_in[20];
  const float* attg = (const float*)d_in[21];
  const float* ga1  = (const float*)d_in[22];
  float* out = (float*)d_out;

  float* ws    = (float*)d_ws;
  float* xmean = ws;                 // 96
  float* sca   = ws + 96;            // 192
  float* ha    = ws + 288;           // 3145728 (later: m, then y2)
  float* hc    = ha + 3145728;       // 3145728 (later: kwA + wp)
  float* x1g   = hc + 3145728;       // 3145728
  float* uf    = x1g + 3145728;      // 3145728
  float* att   = uf + 3145728;       // 1048576
  float* m     = ha;                              // m lifetime [k_gate, k_att2]
  unsigned int* y2 = (unsigned int*)ha;           // y2 lifetime [k_kba, k_proj]
  unsigned short* kwA = (unsigned short*)hc;      // hc dead after k_dw
  unsigned short* wp  = kwA + 98304;              // wproj hi/lo bf16 (9216 u16)

  k_mean<<<96, 256, 0, stream>>>(x, xmean);
  k_sca <<<1, 256, 0, stream>>>(xmean, wsca, bsca, sca);
  k_pw1 <<<dim3(512, 8), 256, 0, stream>>>(x, w1a, b1a, w1c, b1c, w211, b211, ha, hc, att);
  k_dw  <<<12288, 256, 0, stream>>>(ha, hc, wdwa, bdwa, wdwc, bdwc, sca, x1g, uf);
  k_prep<<<402, 256, 0, stream>>>(kbw, kbb, wproj, kwA, wp);
  k_gate<<<1536, 256, 0, stream>>>(x, wc2a, bc2a, m);
  k_att2<<<dim3(512, 4), 256, 0, stream>>>(m, wc2b, bc2b, attg, att);
  k_kba <<<dim3(512, 24), 256, 0, stream>>>(uf, x1g, att, kwA, ga1, y2);
  k_proj<<<512, 256, 0, stream>>>(y2, wp, bproj, out);
}

// Round 14
// 105.853 us; speedup vs baseline: 1.0521x; 1.0521x over previous
//
#include <hip/hip_runtime.h>
#include <math.h>

#define HW 16384
#define Wd 128

typedef __attribute__((ext_vector_type(8))) short short8;
typedef __attribute__((ext_vector_type(4))) float f32x4;

__device__ __forceinline__ unsigned cvt_pk_bf16(float a, float b) {
  unsigned r;                                   // r = bf16(a) | bf16(b)<<16
  asm("v_cvt_pk_bf16_f32 %0, %1, %2" : "=v"(r) : "v"(a), "v"(b));
  return r;
}

__device__ __forceinline__ unsigned short bf16r(float f) {
  unsigned int u = __float_as_uint(f);
  unsigned int r = (u + 0x7FFFu + ((u >> 16) & 1u)) >> 16;   // RNE
  return (unsigned short)r;
}

// ---------------- K1: per (b,c) spatial mean ----------------
__global__ void k_mean(const float* __restrict__ x, float* __restrict__ xmean) {
  int bc = blockIdx.x;                       // 0..95  (b*48+c)
  const float* p = x + (size_t)bc * HW;
  float s = 0.f;
  for (int i = threadIdx.x; i < HW; i += 256) s += p[i];
  #pragma unroll
  for (int off = 32; off > 0; off >>= 1) s += __shfl_down(s, off, 64);
  __shared__ float wsum[4];
  int lane = threadIdx.x & 63, wv = threadIdx.x >> 6;
  if (lane == 0) wsum[wv] = s;
  __syncthreads();
  if (threadIdx.x == 0)
    xmean[bc] = (wsum[0] + wsum[1] + wsum[2] + wsum[3]) * (1.f / 16384.f);
}

__global__ void k_sca(const float* __restrict__ xmean, const float* __restrict__ w_sca,
                      const float* __restrict__ b_sca, float* __restrict__ sca) {
  int t = threadIdx.x;
  if (t < 192) {
    int b = t / 96, co = t % 96;
    float acc = b_sca[co];
    for (int ci = 0; ci < 48; ci++) acc += w_sca[co * 48 + ci] * xmean[b * 48 + ci];
    sca[t] = acc;
  }
}

// ---------------- K3: two 1x1 convs 48->96 + w211 1x1 (a2 of att) ----------------
// grid (512,4): 64 px per block; slot handles 6 h-channels + 2 att channels
__global__ void k_pw1(const float* __restrict__ x,
                      const float* __restrict__ w1a, const float* __restrict__ b1a,
                      const float* __restrict__ w1c, const float* __restrict__ b1c,
                      const float* __restrict__ w211, const float* __restrict__ b211,
                      float* __restrict__ ha, float* __restrict__ hc,
                      float* __restrict__ att) {
  int lane = threadIdx.x & 63;
  int wv = __builtin_amdgcn_readfirstlane((int)(threadIdx.x >> 6));
  int slot = __builtin_amdgcn_readfirstlane((int)(blockIdx.y * 4 + wv));
  int p = blockIdx.x * 64 + lane;
  int b = p >> 14, sp = p & (HW - 1);
  const float* xb = x + (size_t)b * 48 * HW + sp;
  float xv[48];
  #pragma unroll
  for (int ci = 0; ci < 48; ci++) xv[ci] = xb[(size_t)ci * HW];
  float* hab = ha + (size_t)b * 96 * HW + sp;
  float* hcb = hc + (size_t)b * 96 * HW + sp;
  int c0 = slot * 6;
  for (int co = c0; co < c0 + 6; co++) {
    float aa = b1a[co], ac = b1c[co];
    const float* wa = w1a + co * 48;
    const float* wc = w1c + co * 48;
    #pragma unroll
    for (int ci = 0; ci < 48; ci++) { aa += wa[ci] * xv[ci]; ac += wc[ci] * xv[ci]; }
    hab[(size_t)co * HW] = aa;
    hcb[(size_t)co * HW] = ac;
  }
  // a2 part of att: att[n] = b211[n] + w211[n]·x  (a1*gamma added in k_att2)
  float* ab = att + (size_t)b * 32 * HW + sp;
  int n0 = slot * 2;
  for (int n = n0; n < n0 + 2; n++) {
    float a2 = b211[n];
    const float* w2 = w211 + n * 48;
    #pragma unroll
    for (int ci = 0; ci < 48; ci++) a2 += w2[ci] * xv[ci];
    ab[(size_t)n * HW] = a2;
  }
}

// ---------------- K4: depthwise 3x3; x1 path gets gelu*sca folded in ----------------
__global__ void k_dw(const float* __restrict__ ha, const float* __restrict__ hc,
                     const float* __restrict__ wdwa, const float* __restrict__ bdwa,
                     const float* __restrict__ wdwc, const float* __restrict__ bdwc,
                     const float* __restrict__ sca,
                     float* __restrict__ x1g, float* __restrict__ uf) {
  int idx = blockIdx.x * 256 + threadIdx.x;        // < B*96*HW
  int sp = idx & (HW - 1);
  int bc = idx >> 14;                              // b*96+ch
  int ch = bc % 96;
  int r = sp >> 7, c = sp & 127;
  const float* pa = ha + (size_t)bc * HW;
  const float* pc = hc + (size_t)bc * HW;
  float aa = bdwa[ch], ac = bdwc[ch];
  #pragma unroll
  for (int t9 = 0; t9 < 9; t9++) {
    int rr = r + t9 / 3 - 1, cc = c + t9 % 3 - 1;
    bool ok = ((unsigned)rr < 128u) && ((unsigned)cc < 128u);
    float va = ok ? pa[rr * Wd + cc] : 0.f;
    float vc = ok ? pc[rr * Wd + cc] : 0.f;
    aa += wdwa[ch * 9 + t9] * va;
    ac += wdwc[ch * 9 + t9] * vc;
  }
  float gl = aa * 0.5f * (1.f + erff(aa * 0.70710678118654752440f));
  x1g[idx] = gl * sca[bc];
  uf[idx] = ac;
}

// ---------------- K5a: gate m = t1*t2 (grouped 3x3 + SimpleGate) ----------------
__global__ void k_gate(const float* __restrict__ x, const float* __restrict__ wc2a,
                       const float* __restrict__ bc2a, float* __restrict__ m) {
  int idx = blockIdx.x * 256 + threadIdx.x;        // < B*12*HW = 393216
  int sp = idx & (HW - 1);
  int bi = idx >> 14;                              // b*12+i
  int i = bi % 12, b = bi / 12;
  int r = sp >> 7, c = sp & 127;
  const float* xb = x + (size_t)b * 48 * HW;
  float t[2];
  #pragma unroll
  for (int half = 0; half < 2; half++) {
    int o = i + half * 12;
    float acc = bc2a[o];
    #pragma unroll
    for (int ic = 0; ic < 2; ic++) {
      const float* xc = xb + (size_t)(2 * o + ic) * HW;
      const float* wo = wc2a + o * 18 + ic * 9;
      #pragma unroll
      for (int t9 = 0; t9 < 9; t9++) {
        int rr = r + t9 / 3 - 1, cc = c + t9 % 3 - 1;
        float v = (((unsigned)rr < 128u) && ((unsigned)cc < 128u)) ? xc[rr * Wd + cc] : 0.f;
        acc += wo[t9] * v;
      }
    }
    t[half] = acc;
  }
  m[idx] = t[0] * t[1];
}

// ---------------- K5b: att += 1x1(m)*gamma, IN PLACE (a2 already there) ----------
// grid (512,4): slot (0..15) handles 2 att channels; 1:1 thread<->addr, no race
__global__ void k_att2(const float* __restrict__ m,
                       const float* __restrict__ wc2b, const float* __restrict__ bc2b,
                       const float* __restrict__ attg, float* __restrict__ att) {
  int lane = threadIdx.x & 63;
  int wv = __builtin_amdgcn_readfirstlane((int)(threadIdx.x >> 6));
  int slot = __builtin_amdgcn_readfirstlane((int)(blockIdx.y * 4 + wv));
  int p = blockIdx.x * 64 + lane;
  int b = p >> 14, sp = p & (HW - 1);
  float mv[12];
  const float* mb = m + (size_t)b * 12 * HW + sp;
  #pragma unroll
  for (int i = 0; i < 12; i++) mv[i] = mb[(size_t)i * HW];
  float* ab = att + (size_t)b * 32 * HW + sp;
  int n0 = slot * 2;
  for (int n = n0; n < n0 + 2; n++) {
    float a1 = bc2b[n];
    #pragma unroll
    for (int i = 0; i < 12; i++) a1 += wc2b[n * 12 + i] * mv[i];
    float* ap = ab + (size_t)n * HW;
    *ap = a1 * attg[n] + *ap;
  }
}

// ---------------- K_prep: kbw+kbb -> bf16 A-tile [48][64][32]; + wproj hi/lo -----
// blocks 0..383: kwA. blocks 384..401: wp (wproj hi + lo residual).
// K-slot map (center-aligned; q = k>>3, j2 = k&7):
//   q0: j2<5 -> jj = j2 ; q1: j2<5 -> jj = 9+j2 ; q2: j2<4 -> jj = 5+j2 ;
//   q3: j2<4 -> jj = 14+j2, j2==4 -> bias
__global__ void k_prep(const float* __restrict__ kbw, const float* __restrict__ kbb,
                       const float* __restrict__ wproj,
                       unsigned short* __restrict__ kwA, unsigned short* __restrict__ wp) {
  int blk = blockIdx.x;
  if (blk < 384) {
    int e = blk * 256 + threadIdx.x;               // < 98304
    int k = e & 31, nc = (e >> 5) & 63, g = e >> 11;
    int n = nc >> 1, i = nc & 1;
    int q = k >> 3, j2 = k & 7;
    float v = 0.f;
    int jj = -1;
    if (q == 0)      { if (j2 < 5) jj = j2; }
    else if (q == 1) { if (j2 < 5) jj = 9 + j2; }
    else if (q == 2) { if (j2 < 4) jj = 5 + j2; }
    else             { if (j2 < 4) jj = 14 + j2; else if (j2 == 4) v = kbb[n * 96 + 2 * g + i]; }
    if (jj >= 0) v = kbw[n * 1728 + g * 36 + i * 18 + jj];
    kwA[e] = bf16r(v);
  } else {
    int e = (blk - 384) * 256 + threadIdx.x;       // < 4608
    if (e < 4608) {
      float w = wproj[e];
      unsigned short h = bf16r(w);
      wp[e] = h;
      float hif = __uint_as_float((unsigned)h << 16);
      wp[4608 + e] = bf16r(w - hif);
    }
  }
}

// ---------------- K6: fused kba via MFMA (r12 config: 4 groups/block) ----------
// grid (512,12) x 256. Wave wv owns px [wv*16,+16); block covers 4 groups gq*4..+3.
// kwA staged in LDS (16 KB); all loop-body global reads (20 taps, 8 x1g, 8 att)
// prefetched in the preamble -> loop body is pure LDS+MFMA+VALU + y2 stores.
__global__ __launch_bounds__(256) void k_kba(
    const float* __restrict__ uf, const float* __restrict__ x1g,
    const float* __restrict__ att, const unsigned short* __restrict__ kwA,
    const float* __restrict__ ga1, unsigned int* __restrict__ y2) {
  __shared__ __align__(16) short kwS[4 * 2048];    // 16 KB
  int tid = threadIdx.x;
  int lane = tid & 63;
  int wv = tid >> 6;
  int lo = lane & 15, hi = lane >> 4;
  int bid = blockIdx.x;                            // 0..511
  int b = bid >> 8;
  int sp = ((bid & 255) << 6) + wv * 16 + lo;      // this lane's pixel
  int r = sp >> 7, c = sp & 127;
  int g0 = blockIdx.y * 4;

  {
    const short8* src = (const short8*)(kwA + g0 * 2048);
    short8* dst = (short8*)kwS;
    #pragma unroll
    for (int i = 0; i < 4; i++) dst[tid + 256 * i] = src[tid + 256 * i];
  }

  const float* ufb  = uf  + (size_t)b * 96 * HW;
  const float* x1gb = x1g + (size_t)b * 96 * HW;
  const float* attb = att + (size_t)b * 32 * HW;
  unsigned int* y2b = y2 + (size_t)b * 48 * HW;

  float attv[8];
  #pragma unroll
  for (int mt = 0; mt < 4; mt++)
    #pragma unroll
    for (int q = 0; q < 2; q++)
      attv[mt * 2 + q] = attb[(size_t)(8 * mt + 2 * hi + q) * HW + sp];

  const float* pj[5];
  bool ok[5];
  float dv[5];
  #pragma unroll
  for (int j2 = 0; j2 < 5; j2++) {
    int jj = (hi == 0) ? j2 : (hi == 1) ? 9 + j2 : (hi == 2) ? 5 + j2 : 14 + j2;
    bool real = (hi < 2) || (j2 < 4);
    if (real) {
      int ch = jj / 9, tap = jj % 9;
      int rr = r + tap / 3 - 1, cc = c + tap % 3 - 1;
      bool inb = ((unsigned)rr < 128u) && ((unsigned)cc < 128u);
      ok[j2] = inb;
      dv[j2] = 0.f;
      pj[j2] = ufb + (size_t)(2 * g0 + ch) * HW + (inb ? rr * Wd + cc : 0);
    } else {
      ok[j2] = false;
      dv[j2] = (hi == 3) ? 1.f : 0.f;              // bias slot (q3, j2==4)
      pj[j2] = ufb;
    }
  }

  float vT[4][5];
  #pragma unroll
  for (int gi = 0; gi < 4; gi++)
    #pragma unroll
    for (int j2 = 0; j2 < 5; j2++)
      vT[gi][j2] = ok[j2] ? pj[j2][(size_t)(2 * gi) * HW] : dv[j2];
  float x1v[8];
  #pragma unroll
  for (int k = 0; k < 8; k++)
    x1v[k] = x1gb[(size_t)(2 * g0 + k) * HW + sp];

  __syncthreads();

  #pragma unroll
  for (int gp = 0; gp < 2; gp++) {
    int g = g0 + 2 * gp;
    float* va = vT[2 * gp];
    float* vb = vT[2 * gp + 1];
    const short* kgA = kwS + (2 * gp) * 2048;
    const short* kgB = kgA + 2048;
    short8 afrA[4], afrB[4];
    #pragma unroll
    for (int mt = 0; mt < 4; mt++) {
      afrA[mt] = *(const short8*)(kgA + (16 * mt + lo) * 32 + hi * 8);
      afrB[mt] = *(const short8*)(kgB + (16 * mt + lo) * 32 + hi * 8);
    }
    union { unsigned u[4]; short8 s; } bfA, bfB;
    bfA.u[0] = cvt_pk_bf16(va[0], va[1]);
    bfA.u[1] = cvt_pk_bf16(va[2], va[3]);
    bfA.u[2] = cvt_pk_bf16(va[4], 0.f);
    bfA.u[3] = 0u;
    bfB.u[0] = cvt_pk_bf16(vb[0], vb[1]);
    bfB.u[1] = cvt_pk_bf16(vb[2], vb[3]);
    bfB.u[2] = cvt_pk_bf16(vb[4], 0.f);
    bfB.u[3] = 0u;
    f32x4 accA[4], accB[4];
    f32x4 zero = {0.f, 0.f, 0.f, 0.f};
    #pragma unroll
    for (int mt = 0; mt < 4; mt++)
      accA[mt] = __builtin_amdgcn_mfma_f32_16x16x32_bf16(afrA[mt], bfA.s, zero, 0, 0, 0);
    #pragma unroll
    for (int mt = 0; mt < 4; mt++)
      accB[mt] = __builtin_amdgcn_mfma_f32_16x16x32_bf16(afrB[mt], bfB.s, zero, 0, 0, 0);
    float sA0 = 0.f, sA1 = 0.f, sB0 = 0.f, sB1 = 0.f;
    #pragma unroll
    for (int mt = 0; mt < 4; mt++) {
      sA0 += attv[mt * 2 + 0] * accA[mt][0] + attv[mt * 2 + 1] * accA[mt][2];
      sA1 += attv[mt * 2 + 0] * accA[mt][1] + attv[mt * 2 + 1] * accA[mt][3];
    }
    sA0 += __shfl_xor(sA0, 16); sA0 += __shfl_xor(sA0, 32);
    sA1 += __shfl_xor(sA1, 16); sA1 += __shfl_xor(sA1, 32);
    float cenA = __shfl_xor(va[4], 16);
    #pragma unroll
    for (int mt = 0; mt < 4; mt++) {
      sB0 += attv[mt * 2 + 0] * accB[mt][0] + attv[mt * 2 + 1] * accB[mt][2];
      sB1 += attv[mt * 2 + 0] * accB[mt][1] + attv[mt * 2 + 1] * accB[mt][3];
    }
    sB0 += __shfl_xor(sB0, 16); sB0 += __shfl_xor(sB0, 32);
    sB1 += __shfl_xor(sB1, 16); sB1 += __shfl_xor(sB1, 32);
    float cenB = __shfl_xor(vb[4], 16);
    if (hi == 0) {
      int c0 = 2 * g;
      float xa0 = sA0 * ga1[c0]     + va[4];
      float xa1 = sA1 * ga1[c0 + 1] + cenA;
      float ya0 = x1v[4 * gp]     * xa0;
      float ya1 = x1v[4 * gp + 1] * xa1;
      y2b[(size_t)g * HW + sp] = cvt_pk_bf16(ya0, ya1);
      float xb0 = sB0 * ga1[c0 + 2] + vb[4];
      float xb1 = sB1 * ga1[c0 + 3] + cenB;
      float yb0 = x1v[4 * gp + 2] * xb0;
      float yb1 = x1v[4 * gp + 3] * xb1;
      y2b[(size_t)(g + 1) * HW + sp] = cvt_pk_bf16(yb0, yb1);
    }
  }
}

// ---------------- K7: project_out 96->48 via MFMA (W = bf16 hi + bf16 lo) -------
// grid 512 x 256. Wave handles 16 px, all 48 out-channels (3 row-tiles).
__global__ void k_proj(const unsigned int* __restrict__ y2, const unsigned short* __restrict__ wp,
                       const float* __restrict__ bproj, float* __restrict__ out) {
  int tid = threadIdx.x;
  int lane = tid & 63;
  int wv = tid >> 6;
  int lo = lane & 15, hi = lane >> 4;
  int p0 = blockIdx.x * 64 + wv * 16;
  int b = p0 >> 14;
  int sp = (p0 & (HW - 1)) + lo;
  const unsigned int* yb = y2 + (size_t)b * 48 * HW + sp;
  union { unsigned u[4]; short8 s; } bf[3];
  #pragma unroll
  for (int ks = 0; ks < 3; ks++)
    #pragma unroll
    for (int q = 0; q < 4; q++)
      bf[ks].u[q] = yb[(size_t)(ks * 16 + hi * 4 + q) * HW];
  f32x4 acc[3];
  #pragma unroll
  for (int t = 0; t < 3; t++)
    #pragma unroll
    for (int r = 0; r < 4; r++)
      acc[t][r] = bproj[16 * t + 4 * hi + r];
  #pragma unroll
  for (int t = 0; t < 3; t++) {
    #pragma unroll
    for (int ks = 0; ks < 3; ks++) {
      short8 ah = *(const short8*)(wp + (16 * t + lo) * 96 + ks * 32 + hi * 8);
      acc[t] = __builtin_amdgcn_mfma_f32_16x16x32_bf16(ah, bf[ks].s, acc[t], 0, 0, 0);
      short8 al = *(const short8*)(wp + 4608 + (16 * t + lo) * 96 + ks * 32 + hi * 8);
      acc[t] = __builtin_amdgcn_mfma_f32_16x16x32_bf16(al, bf[ks].s, acc[t], 0, 0, 0);
    }
  }
  float* ob = out + (size_t)b * 48 * HW + sp;
  #pragma unroll
  for (int t = 0; t < 3; t++)
    #pragma unroll
    for (int r = 0; r < 4; r++)
      ob[(size_t)(16 * t + 4 * hi + r) * HW] = acc[t][r];
}

extern "C" void kernel_launch(void* const* d_in, const int* in_sizes, int n_in,
                              void* d_out, int out_size, void* d_ws, size_t ws_size,
                              hipStream_t stream) {
  const float* x    = (const float*)d_in[0];
  const float* w1a  = (const float*)d_in[1];
  const float* b1a  = (const float*)d_in[2];
  const float* wdwa = (const float*)d_in[3];
  const float* bdwa = (const float*)d_in[4];
  const float* w1c  = (const float*)d_in[5];
  const float* b1c  = (const float*)d_in[6];
  const float* wdwc = (const float*)d_in[7];
  const float* bdwc = (const float*)d_in[8];
  const float* wsca = (const float*)d_in[9];
  const float* bsca = (const float*)d_in[10];
  const float* wc2a = (const float*)d_in[11];
  const float* bc2a = (const float*)d_in[12];
  const float* wc2b = (const float*)d_in[13];
  const float* bc2b = (const float*)d_in[14];
  const float* w211 = (const float*)d_in[15];
  const float* b211 = (const float*)d_in[16];
  const float* wproj= (const float*)d_in[17];
  const float* bproj= (const float*)d_in[18];
  const float* kbw  = (const float*)d_in[19];
  const float* kbb  = (const float*)d_in[20];
  const float* attg = (const float*)d_in[21];
  const float* ga1  = (const float*)d_in[22];
  float* out = (float*)d_out;

  float* ws    = (float*)d_ws;
  float* xmean = ws;                 // 96
  float* sca   = ws + 96;            // 192
  float* ha    = ws + 288;           // 3145728 (later: m, then y2)
  float* hc    = ha + 3145728;       // 3145728 (later: kwA + wp)
  float* x1g   = hc + 3145728;       // 3145728
  float* uf    = x1g + 3145728;      // 3145728
  float* att   = uf + 3145728;       // 1048576
  float* m     = ha;                              // m lifetime [k_gate, k_att2]
  unsigned int* y2 = (unsigned int*)ha;           // y2 lifetime [k_kba, k_proj]
  unsigned short* kwA = (unsigned short*)hc;      // hc dead after k_dw
  unsigned short* wp  = kwA + 98304;              // wproj hi/lo bf16 (9216 u16)

  k_mean<<<96, 256, 0, stream>>>(x, xmean);
  k_sca <<<1, 256, 0, stream>>>(xmean, wsca, bsca, sca);
  k_pw1 <<<dim3(512, 4), 256, 0, stream>>>(x, w1a, b1a, w1c, b1c, w211, b211, ha, hc, att);
  k_dw  <<<12288, 256, 0, stream>>>(ha, hc, wdwa, bdwa, wdwc, bdwc, sca, x1g, uf);
  k_prep<<<402, 256, 0, stream>>>(kbw, kbb, wproj, kwA, wp);
  k_gate<<<1536, 256, 0, stream>>>(x, wc2a, bc2a, m);
  k_att2<<<dim3(512, 4), 256, 0, stream>>>(m, wc2b, bc2b, attg, att);
  k_kba <<<dim3(512, 12), 256, 0, stream>>>(uf, x1g, att, kwA, ga1, y2);
  k_proj<<<512, 256, 0, stream>>>(y2, wp, bproj, out);
}

// Round 15
// 104.743 us; speedup vs baseline: 1.0633x; 1.0106x over previous
//
#include <hip/hip_runtime.h>
#include <math.h>

#define HW 16384
#define Wd 128

typedef __attribute__((ext_vector_type(8))) short short8;
typedef __attribute__((ext_vector_type(4))) float f32x4;

__device__ __forceinline__ unsigned cvt_pk_bf16(float a, float b) {
  unsigned r;                                   // r = bf16(a) | bf16(b)<<16
  asm("v_cvt_pk_bf16_f32 %0, %1, %2" : "=v"(r) : "v"(a), "v"(b));
  return r;
}

__device__ __forceinline__ unsigned short bf16r(float f) {
  unsigned int u = __float_as_uint(f);
  unsigned int r = (u + 0x7FFFu + ((u >> 16) & 1u)) >> 16;   // RNE
  return (unsigned short)r;
}

// ---------------- K1: per (b,c) spatial mean ----------------
__global__ void k_mean(const float* __restrict__ x, float* __restrict__ xmean) {
  int bc = blockIdx.x;                       // 0..95  (b*48+c)
  const float* p = x + (size_t)bc * HW;
  float s = 0.f;
  for (int i = threadIdx.x; i < HW; i += 256) s += p[i];
  #pragma unroll
  for (int off = 32; off > 0; off >>= 1) s += __shfl_down(s, off, 64);
  __shared__ float wsum[4];
  int lane = threadIdx.x & 63, wv = threadIdx.x >> 6;
  if (lane == 0) wsum[wv] = s;
  __syncthreads();
  if (threadIdx.x == 0)
    xmean[bc] = (wsum[0] + wsum[1] + wsum[2] + wsum[3]) * (1.f / 16384.f);
}

__global__ void k_sca(const float* __restrict__ xmean, const float* __restrict__ w_sca,
                      const float* __restrict__ b_sca, float* __restrict__ sca) {
  int t = threadIdx.x;
  if (t < 192) {
    int b = t / 96, co = t % 96;
    float acc = b_sca[co];
    for (int ci = 0; ci < 48; ci++) acc += w_sca[co * 48 + ci] * xmean[b * 48 + ci];
    sca[t] = acc;
  }
}

// ---------------- K3: two 1x1 convs 48->96 + w211 1x1 (a2 of att) ----------------
// grid (512,4): 64 px per block; slot handles 6 h-channels + 2 att channels
__global__ void k_pw1(const float* __restrict__ x,
                      const float* __restrict__ w1a, const float* __restrict__ b1a,
                      const float* __restrict__ w1c, const float* __restrict__ b1c,
                      const float* __restrict__ w211, const float* __restrict__ b211,
                      float* __restrict__ ha, float* __restrict__ hc,
                      float* __restrict__ att) {
  int lane = threadIdx.x & 63;
  int wv = __builtin_amdgcn_readfirstlane((int)(threadIdx.x >> 6));
  int slot = __builtin_amdgcn_readfirstlane((int)(blockIdx.y * 4 + wv));
  int p = blockIdx.x * 64 + lane;
  int b = p >> 14, sp = p & (HW - 1);
  const float* xb = x + (size_t)b * 48 * HW + sp;
  float xv[48];
  #pragma unroll
  for (int ci = 0; ci < 48; ci++) xv[ci] = xb[(size_t)ci * HW];
  float* hab = ha + (size_t)b * 96 * HW + sp;
  float* hcb = hc + (size_t)b * 96 * HW + sp;
  int c0 = slot * 6;
  for (int co = c0; co < c0 + 6; co++) {
    float aa = b1a[co], ac = b1c[co];
    const float* wa = w1a + co * 48;
    const float* wc = w1c + co * 48;
    #pragma unroll
    for (int ci = 0; ci < 48; ci++) { aa += wa[ci] * xv[ci]; ac += wc[ci] * xv[ci]; }
    hab[(size_t)co * HW] = aa;
    hcb[(size_t)co * HW] = ac;
  }
  // a2 part of att: att[n] = b211[n] + w211[n]·x  (a1*gamma added in k_att2)
  float* ab = att + (size_t)b * 32 * HW + sp;
  int n0 = slot * 2;
  for (int n = n0; n < n0 + 2; n++) {
    float a2 = b211[n];
    const float* w2 = w211 + n * 48;
    #pragma unroll
    for (int ci = 0; ci < 48; ci++) a2 += w2[ci] * xv[ci];
    ab[(size_t)n * HW] = a2;
  }
}

// ---------------- K4: depthwise 3x3, 4-px column strips ----------------
// One thread per (bc, 4-col strip). Per row+array: one aligned float4 (c..c+3)
// plus two edge scalars gives taps c-1..c+4 for 4 outputs. Row predicate is
// wave-uniform; weights are block-uniform (scalar loads). 12288 waves.
__global__ void k_dw(const float* __restrict__ ha, const float* __restrict__ hc,
                     const float* __restrict__ wdwa, const float* __restrict__ bdwa,
                     const float* __restrict__ wdwc, const float* __restrict__ bdwc,
                     const float* __restrict__ sca,
                     float* __restrict__ x1g, float* __restrict__ uf) {
  int idx = blockIdx.x * 256 + threadIdx.x;        // < B*96*HW/4 = 786432
  int sp4 = idx & 4095;
  int bc = idx >> 12;                              // b*96+ch (block-uniform)
  int ch = bc % 96;
  int sp = sp4 * 4;
  int r = sp >> 7, c = sp & 127;                   // c in {0,4,...,124}
  const float* pa = ha + (size_t)bc * HW;
  const float* pc = hc + (size_t)bc * HW;
  bool cm = (c > 0), cp = (c < 124);
  float aa0 = bdwa[ch], aa1 = aa0, aa2 = aa0, aa3 = aa0;
  float gc0 = bdwc[ch], gc1 = gc0, gc2 = gc0, gc3 = gc0;
  #pragma unroll
  for (int ri = 0; ri < 3; ri++) {
    int rr = r + ri - 1;
    bool okr = ((unsigned)rr < 128u);
    const float* ra = pa + rr * Wd + c;
    const float* rc = pc + rr * Wd + c;
    float4 fa = okr ? *(const float4*)ra : make_float4(0.f, 0.f, 0.f, 0.f);
    float4 fc = okr ? *(const float4*)rc : make_float4(0.f, 0.f, 0.f, 0.f);
    float la = (okr && cm) ? ra[-1] : 0.f;
    float lc = (okr && cm) ? rc[-1] : 0.f;
    float ua = (okr && cp) ? ra[4] : 0.f;
    float uc = (okr && cp) ? rc[4] : 0.f;
    float wa0 = wdwa[ch * 9 + ri * 3], wa1 = wdwa[ch * 9 + ri * 3 + 1], wa2 = wdwa[ch * 9 + ri * 3 + 2];
    float wc0 = wdwc[ch * 9 + ri * 3], wc1 = wdwc[ch * 9 + ri * 3 + 1], wc2 = wdwc[ch * 9 + ri * 3 + 2];
    aa0 += wa0 * la   + wa1 * fa.x + wa2 * fa.y;
    aa1 += wa0 * fa.x + wa1 * fa.y + wa2 * fa.z;
    aa2 += wa0 * fa.y + wa1 * fa.z + wa2 * fa.w;
    aa3 += wa0 * fa.z + wa1 * fa.w + wa2 * ua;
    gc0 += wc0 * lc   + wc1 * fc.x + wc2 * fc.y;
    gc1 += wc0 * fc.x + wc1 * fc.y + wc2 * fc.z;
    gc2 += wc0 * fc.y + wc1 * fc.z + wc2 * fc.w;
    gc3 += wc0 * fc.z + wc1 * fc.w + wc2 * uc;
  }
  float sc = sca[bc];
  const float k = 0.70710678118654752440f;
  float4 xg;
  xg.x = aa0 * 0.5f * (1.f + erff(aa0 * k)) * sc;
  xg.y = aa1 * 0.5f * (1.f + erff(aa1 * k)) * sc;
  xg.z = aa2 * 0.5f * (1.f + erff(aa2 * k)) * sc;
  xg.w = aa3 * 0.5f * (1.f + erff(aa3 * k)) * sc;
  *(float4*)(x1g + (size_t)bc * HW + sp) = xg;
  *(float4*)(uf + (size_t)bc * HW + sp) = make_float4(gc0, gc1, gc2, gc3);
}

// ---------------- K5a: gate m = t1*t2 (grouped 3x3 + SimpleGate) ----------------
__global__ void k_gate(const float* __restrict__ x, const float* __restrict__ wc2a,
                       const float* __restrict__ bc2a, float* __restrict__ m) {
  int idx = blockIdx.x * 256 + threadIdx.x;        // < B*12*HW = 393216
  int sp = idx & (HW - 1);
  int bi = idx >> 14;                              // b*12+i
  int i = bi % 12, b = bi / 12;
  int r = sp >> 7, c = sp & 127;
  const float* xb = x + (size_t)b * 48 * HW;
  float t[2];
  #pragma unroll
  for (int half = 0; half < 2; half++) {
    int o = i + half * 12;
    float acc = bc2a[o];
    #pragma unroll
    for (int ic = 0; ic < 2; ic++) {
      const float* xc = xb + (size_t)(2 * o + ic) * HW;
      const float* wo = wc2a + o * 18 + ic * 9;
      #pragma unroll
      for (int t9 = 0; t9 < 9; t9++) {
        int rr = r + t9 / 3 - 1, cc = c + t9 % 3 - 1;
        float v = (((unsigned)rr < 128u) && ((unsigned)cc < 128u)) ? xc[rr * Wd + cc] : 0.f;
        acc += wo[t9] * v;
      }
    }
    t[half] = acc;
  }
  m[idx] = t[0] * t[1];
}

// ---------------- K5b: att += 1x1(m)*gamma, IN PLACE (a2 already there) ----------
// grid (512,4): slot (0..15) handles 2 att channels; 1:1 thread<->addr, no race
__global__ void k_att2(const float* __restrict__ m,
                       const float* __restrict__ wc2b, const float* __restrict__ bc2b,
                       const float* __restrict__ attg, float* __restrict__ att) {
  int lane = threadIdx.x & 63;
  int wv = __builtin_amdgcn_readfirstlane((int)(threadIdx.x >> 6));
  int slot = __builtin_amdgcn_readfirstlane((int)(blockIdx.y * 4 + wv));
  int p = blockIdx.x * 64 + lane;
  int b = p >> 14, sp = p & (HW - 1);
  float mv[12];
  const float* mb = m + (size_t)b * 12 * HW + sp;
  #pragma unroll
  for (int i = 0; i < 12; i++) mv[i] = mb[(size_t)i * HW];
  float* ab = att + (size_t)b * 32 * HW + sp;
  int n0 = slot * 2;
  for (int n = n0; n < n0 + 2; n++) {
    float a1 = bc2b[n];
    #pragma unroll
    for (int i = 0; i < 12; i++) a1 += wc2b[n * 12 + i] * mv[i];
    float* ap = ab + (size_t)n * HW;
    *ap = a1 * attg[n] + *ap;
  }
}

// ---------------- K_prep: kbw+kbb -> bf16 A-tile [48][64][32]; + wproj hi/lo -----
// blocks 0..383: kwA. blocks 384..401: wp (wproj hi + lo residual).
// K-slot map (center-aligned; q = k>>3, j2 = k&7):
//   q0: j2<5 -> jj = j2 ; q1: j2<5 -> jj = 9+j2 ; q2: j2<4 -> jj = 5+j2 ;
//   q3: j2<4 -> jj = 14+j2, j2==4 -> bias
__global__ void k_prep(const float* __restrict__ kbw, const float* __restrict__ kbb,
                       const float* __restrict__ wproj,
                       unsigned short* __restrict__ kwA, unsigned short* __restrict__ wp) {
  int blk = blockIdx.x;
  if (blk < 384) {
    int e = blk * 256 + threadIdx.x;               // < 98304
    int k = e & 31, nc = (e >> 5) & 63, g = e >> 11;
    int n = nc >> 1, i = nc & 1;
    int q = k >> 3, j2 = k & 7;
    float v = 0.f;
    int jj = -1;
    if (q == 0)      { if (j2 < 5) jj = j2; }
    else if (q == 1) { if (j2 < 5) jj = 9 + j2; }
    else if (q == 2) { if (j2 < 4) jj = 5 + j2; }
    else             { if (j2 < 4) jj = 14 + j2; else if (j2 == 4) v = kbb[n * 96 + 2 * g + i]; }
    if (jj >= 0) v = kbw[n * 1728 + g * 36 + i * 18 + jj];
    kwA[e] = bf16r(v);
  } else {
    int e = (blk - 384) * 256 + threadIdx.x;       // < 4608
    if (e < 4608) {
      float w = wproj[e];
      unsigned short h = bf16r(w);
      wp[e] = h;
      float hif = __uint_as_float((unsigned)h << 16);
      wp[4608 + e] = bf16r(w - hif);
    }
  }
}

// ---------------- K6: fused kba via MFMA (4 groups/block) ----------
// grid (512,12) x 256. Wave wv owns px [wv*16,+16); block covers 4 groups gq*4..+3.
// kwA staged in LDS (16 KB); all loop-body global reads (20 taps, 8 x1g, 8 att)
// prefetched in the preamble -> loop body is pure LDS+MFMA+VALU + y2 stores.
__global__ __launch_bounds__(256) void k_kba(
    const float* __restrict__ uf, const float* __restrict__ x1g,
    const float* __restrict__ att, const unsigned short* __restrict__ kwA,
    const float* __restrict__ ga1, unsigned int* __restrict__ y2) {
  __shared__ __align__(16) short kwS[4 * 2048];    // 16 KB
  int tid = threadIdx.x;
  int lane = tid & 63;
  int wv = tid >> 6;
  int lo = lane & 15, hi = lane >> 4;
  int bid = blockIdx.x;                            // 0..511
  int b = bid >> 8;
  int sp = ((bid & 255) << 6) + wv * 16 + lo;      // this lane's pixel
  int r = sp >> 7, c = sp & 127;
  int g0 = blockIdx.y * 4;

  {
    const short8* src = (const short8*)(kwA + g0 * 2048);
    short8* dst = (short8*)kwS;
    #pragma unroll
    for (int i = 0; i < 4; i++) dst[tid + 256 * i] = src[tid + 256 * i];
  }

  const float* ufb  = uf  + (size_t)b * 96 * HW;
  const float* x1gb = x1g + (size_t)b * 96 * HW;
  const float* attb = att + (size_t)b * 32 * HW;
  unsigned int* y2b = y2 + (size_t)b * 48 * HW;

  float attv[8];
  #pragma unroll
  for (int mt = 0; mt < 4; mt++)
    #pragma unroll
    for (int q = 0; q < 2; q++)
      attv[mt * 2 + q] = attb[(size_t)(8 * mt + 2 * hi + q) * HW + sp];

  const float* pj[5];
  bool ok[5];
  float dv[5];
  #pragma unroll
  for (int j2 = 0; j2 < 5; j2++) {
    int jj = (hi == 0) ? j2 : (hi == 1) ? 9 + j2 : (hi == 2) ? 5 + j2 : 14 + j2;
    bool real = (hi < 2) || (j2 < 4);
    if (real) {
      int ch = jj / 9, tap = jj % 9;
      int rr = r + tap / 3 - 1, cc = c + tap % 3 - 1;
      bool inb = ((unsigned)rr < 128u) && ((unsigned)cc < 128u);
      ok[j2] = inb;
      dv[j2] = 0.f;
      pj[j2] = ufb + (size_t)(2 * g0 + ch) * HW + (inb ? rr * Wd + cc : 0);
    } else {
      ok[j2] = false;
      dv[j2] = (hi == 3) ? 1.f : 0.f;              // bias slot (q3, j2==4)
      pj[j2] = ufb;
    }
  }

  float vT[4][5];
  #pragma unroll
  for (int gi = 0; gi < 4; gi++)
    #pragma unroll
    for (int j2 = 0; j2 < 5; j2++)
      vT[gi][j2] = ok[j2] ? pj[j2][(size_t)(2 * gi) * HW] : dv[j2];
  float x1v[8];
  #pragma unroll
  for (int k = 0; k < 8; k++)
    x1v[k] = x1gb[(size_t)(2 * g0 + k) * HW + sp];

  __syncthreads();

  #pragma unroll
  for (int gp = 0; gp < 2; gp++) {
    int g = g0 + 2 * gp;
    float* va = vT[2 * gp];
    float* vb = vT[2 * gp + 1];
    const short* kgA = kwS + (2 * gp) * 2048;
    const short* kgB = kgA + 2048;
    short8 afrA[4], afrB[4];
    #pragma unroll
    for (int mt = 0; mt < 4; mt++) {
      afrA[mt] = *(const short8*)(kgA + (16 * mt + lo) * 32 + hi * 8);
      afrB[mt] = *(const short8*)(kgB + (16 * mt + lo) * 32 + hi * 8);
    }
    union { unsigned u[4]; short8 s; } bfA, bfB;
    bfA.u[0] = cvt_pk_bf16(va[0], va[1]);
    bfA.u[1] = cvt_pk_bf16(va[2], va[3]);
    bfA.u[2] = cvt_pk_bf16(va[4], 0.f);
    bfA.u[3] = 0u;
    bfB.u[0] = cvt_pk_bf16(vb[0], vb[1]);
    bfB.u[1] = cvt_pk_bf16(vb[2], vb[3]);
    bfB.u[2] = cvt_pk_bf16(vb[4], 0.f);
    bfB.u[3] = 0u;
    f32x4 accA[4], accB[4];
    f32x4 zero = {0.f, 0.f, 0.f, 0.f};
    #pragma unroll
    for (int mt = 0; mt < 4; mt++)
      accA[mt] = __builtin_amdgcn_mfma_f32_16x16x32_bf16(afrA[mt], bfA.s, zero, 0, 0, 0);
    #pragma unroll
    for (int mt = 0; mt < 4; mt++)
      accB[mt] = __builtin_amdgcn_mfma_f32_16x16x32_bf16(afrB[mt], bfB.s, zero, 0, 0, 0);
    float sA0 = 0.f, sA1 = 0.f, sB0 = 0.f, sB1 = 0.f;
    #pragma unroll
    for (int mt = 0; mt < 4; mt++) {
      sA0 += attv[mt * 2 + 0] * accA[mt][0] + attv[mt * 2 + 1] * accA[mt][2];
      sA1 += attv[mt * 2 + 0] * accA[mt][1] + attv[mt * 2 + 1] * accA[mt][3];
    }
    sA0 += __shfl_xor(sA0, 16); sA0 += __shfl_xor(sA0, 32);
    sA1 += __shfl_xor(sA1, 16); sA1 += __shfl_xor(sA1, 32);
    float cenA = __shfl_xor(va[4], 16);
    #pragma unroll
    for (int mt = 0; mt < 4; mt++) {
      sB0 += attv[mt * 2 + 0] * accB[mt][0] + attv[mt * 2 + 1] * accB[mt][2];
      sB1 += attv[mt * 2 + 0] * accB[mt][1] + attv[mt * 2 + 1] * accB[mt][3];
    }
    sB0 += __shfl_xor(sB0, 16); sB0 += __shfl_xor(sB0, 32);
    sB1 += __shfl_xor(sB1, 16); sB1 += __shfl_xor(sB1, 32);
    float cenB = __shfl_xor(vb[4], 16);
    if (hi == 0) {
      int c0 = 2 * g;
      float xa0 = sA0 * ga1[c0]     + va[4];
      float xa1 = sA1 * ga1[c0 + 1] + cenA;
      float ya0 = x1v[4 * gp]     * xa0;
      float ya1 = x1v[4 * gp + 1] * xa1;
      y2b[(size_t)g * HW + sp] = cvt_pk_bf16(ya0, ya1);
      float xb0 = sB0 * ga1[c0 + 2] + vb[4];
      float xb1 = sB1 * ga1[c0 + 3] + cenB;
      float yb0 = x1v[4 * gp + 2] * xb0;
      float yb1 = x1v[4 * gp + 3] * xb1;
      y2b[(size_t)(g + 1) * HW + sp] = cvt_pk_bf16(yb0, yb1);
    }
  }
}

// ---------------- K7: project_out 96->48 via MFMA (W = bf16 hi + bf16 lo) -------
// grid 512 x 256. Wave handles 16 px, all 48 out-channels (3 row-tiles).
__global__ void k_proj(const unsigned int* __restrict__ y2, const unsigned short* __restrict__ wp,
                       const float* __restrict__ bproj, float* __restrict__ out) {
  int tid = threadIdx.x;
  int lane = tid & 63;
  int wv = tid >> 6;
  int lo = lane & 15, hi = lane >> 4;
  int p0 = blockIdx.x * 64 + wv * 16;
  int b = p0 >> 14;
  int sp = (p0 & (HW - 1)) + lo;
  const unsigned int* yb = y2 + (size_t)b * 48 * HW + sp;
  union { unsigned u[4]; short8 s; } bf[3];
  #pragma unroll
  for (int ks = 0; ks < 3; ks++)
    #pragma unroll
    for (int q = 0; q < 4; q++)
      bf[ks].u[q] = yb[(size_t)(ks * 16 + hi * 4 + q) * HW];
  f32x4 acc[3];
  #pragma unroll
  for (int t = 0; t < 3; t++)
    #pragma unroll
    for (int r = 0; r < 4; r++)
      acc[t][r] = bproj[16 * t + 4 * hi + r];
  #pragma unroll
  for (int t = 0; t < 3; t++) {
    #pragma unroll
    for (int ks = 0; ks < 3; ks++) {
      short8 ah = *(const short8*)(wp + (16 * t + lo) * 96 + ks * 32 + hi * 8);
      acc[t] = __builtin_amdgcn_mfma_f32_16x16x32_bf16(ah, bf[ks].s, acc[t], 0, 0, 0);
      short8 al = *(const short8*)(wp + 4608 + (16 * t + lo) * 96 + ks * 32 + hi * 8);
      acc[t] = __builtin_amdgcn_mfma_f32_16x16x32_bf16(al, bf[ks].s, acc[t], 0, 0, 0);
    }
  }
  float* ob = out + (size_t)b * 48 * HW + sp;
  #pragma unroll
  for (int t = 0; t < 3; t++)
    #pragma unroll
    for (int r = 0; r < 4; r++)
      ob[(size_t)(16 * t + 4 * hi + r) * HW] = acc[t][r];
}

extern "C" void kernel_launch(void* const* d_in, const int* in_sizes, int n_in,
                              void* d_out, int out_size, void* d_ws, size_t ws_size,
                              hipStream_t stream) {
  const float* x    = (const float*)d_in[0];
  const float* w1a  = (const float*)d_in[1];
  const float* b1a  = (const float*)d_in[2];
  const float* wdwa = (const float*)d_in[3];
  const float* bdwa = (const float*)d_in[4];
  const float* w1c  = (const float*)d_in[5];
  const float* b1c  = (const float*)d_in[6];
  const float* wdwc = (const float*)d_in[7];
  const float* bdwc = (const float*)d_in[8];
  const float* wsca = (const float*)d_in[9];
  const float* bsca = (const float*)d_in[10];
  const float* wc2a = (const float*)d_in[11];
  const float* bc2a = (const float*)d_in[12];
  const float* wc2b = (const float*)d_in[13];
  const float* bc2b = (const float*)d_in[14];
  const float* w211 = (const float*)d_in[15];
  const float* b211 = (const float*)d_in[16];
  const float* wproj= (const float*)d_in[17];
  const float* bproj= (const float*)d_in[18];
  const float* kbw  = (const float*)d_in[19];
  const float* kbb  = (const float*)d_in[20];
  const float* attg = (const float*)d_in[21];
  const float* ga1  = (const float*)d_in[22];
  float* out = (float*)d_out;

  float* ws    = (float*)d_ws;
  float* xmean = ws;                 // 96
  float* sca   = ws + 96;            // 192
  float* ha    = ws + 288;           // 3145728 (later: m, then y2)
  float* hc    = ha + 3145728;       // 3145728 (later: kwA + wp)
  float* x1g   = hc + 3145728;       // 3145728
  float* uf    = x1g + 3145728;      // 3145728
  float* att   = uf + 3145728;       // 1048576
  float* m     = ha;                              // m lifetime [k_gate, k_att2]
  unsigned int* y2 = (unsigned int*)ha;           // y2 lifetime [k_kba, k_proj]
  unsigned short* kwA = (unsigned short*)hc;      // hc dead after k_dw
  unsigned short* wp  = kwA + 98304;              // wproj hi/lo bf16 (9216 u16)

  k_mean<<<96, 256, 0, stream>>>(x, xmean);
  k_sca <<<1, 256, 0, stream>>>(xmean, wsca, bsca, sca);
  k_pw1 <<<dim3(512, 4), 256, 0, stream>>>(x, w1a, b1a, w1c, b1c, w211, b211, ha, hc, att);
  k_dw  <<<3072, 256, 0, stream>>>(ha, hc, wdwa, bdwa, wdwc, bdwc, sca, x1g, uf);
  k_prep<<<402, 256, 0, stream>>>(kbw, kbb, wproj, kwA, wp);
  k_gate<<<1536, 256, 0, stream>>>(x, wc2a, bc2a, m);
  k_att2<<<dim3(512, 4), 256, 0, stream>>>(m, wc2b, bc2b, attg, att);
  k_kba <<<dim3(512, 12), 256, 0, stream>>>(uf, x1g, att, kwA, ga1, y2);
  k_proj<<<512, 256, 0, stream>>>(y2, wp, bproj, out);
}

// Round 16
// 81.140 us; speedup vs baseline: 1.3726x; 1.2909x over previous
//
#include <hip/hip_runtime.h>
#include <math.h>

#define HW 16384
#define Wd 128

typedef __attribute__((ext_vector_type(8))) short short8;
typedef __attribute__((ext_vector_type(4))) float f32x4;

__device__ __forceinline__ unsigned cvt_pk_bf16(float a, float b) {
  unsigned r;                                   // r = bf16(a) | bf16(b)<<16
  asm("v_cvt_pk_bf16_f32 %0, %1, %2" : "=v"(r) : "v"(a), "v"(b));
  return r;
}

__device__ __forceinline__ unsigned short bf16r(float f) {
  unsigned int u = __float_as_uint(f);
  unsigned int r = (u + 0x7FFFu + ((u >> 16) & 1u)) >> 16;   // RNE
  return (unsigned short)r;
}

// ================= LAUNCH 1: mean | pw1 | prep | gate (block ranges) =========
// [0,96): per-(b,c) spatial mean -> xmean
// [96,2144): pw1 -> ha, hc, att(a2 part)
// [2144,2546): prep -> kwA, wp
// [2546,4082): gate -> m
__global__ void k_combo1(
    const float* __restrict__ x,
    const float* __restrict__ w1a, const float* __restrict__ b1a,
    const float* __restrict__ w1c, const float* __restrict__ b1c,
    const float* __restrict__ w211, const float* __restrict__ b211,
    const float* __restrict__ kbw, const float* __restrict__ kbb,
    const float* __restrict__ wproj,
    const float* __restrict__ wc2a, const float* __restrict__ bc2a,
    float* __restrict__ xmean, float* __restrict__ ha, float* __restrict__ hc,
    float* __restrict__ att, unsigned short* __restrict__ kwA,
    unsigned short* __restrict__ wp, float* __restrict__ m) {
  int blk = blockIdx.x;
  int tid = threadIdx.x;
  if (blk < 96) {
    // ---- mean ----
    int bc = blk;
    const float* p = x + (size_t)bc * HW;
    float s = 0.f;
    for (int i = tid; i < HW; i += 256) s += p[i];
    #pragma unroll
    for (int off = 32; off > 0; off >>= 1) s += __shfl_down(s, off, 64);
    __shared__ float wsum[4];
    int lane = tid & 63, wv = tid >> 6;
    if (lane == 0) wsum[wv] = s;
    __syncthreads();
    if (tid == 0)
      xmean[bc] = (wsum[0] + wsum[1] + wsum[2] + wsum[3]) * (1.f / 16384.f);
  } else if (blk < 2144) {
    // ---- pw1 (flattened (512,4)) ----
    int bid2 = blk - 96;
    int bx = bid2 & 511, quad = bid2 >> 9;
    int lane = tid & 63;
    int wv = __builtin_amdgcn_readfirstlane((int)(tid >> 6));
    int slot = __builtin_amdgcn_readfirstlane(quad * 4 + wv);
    int p = bx * 64 + lane;
    int b = p >> 14, sp = p & (HW - 1);
    const float* xb = x + (size_t)b * 48 * HW + sp;
    float xv[48];
    #pragma unroll
    for (int ci = 0; ci < 48; ci++) xv[ci] = xb[(size_t)ci * HW];
    float* hab = ha + (size_t)b * 96 * HW + sp;
    float* hcb = hc + (size_t)b * 96 * HW + sp;
    int c0 = slot * 6;
    for (int co = c0; co < c0 + 6; co++) {
      float aa = b1a[co], ac = b1c[co];
      const float* wa = w1a + co * 48;
      const float* wc = w1c + co * 48;
      #pragma unroll
      for (int ci = 0; ci < 48; ci++) { aa += wa[ci] * xv[ci]; ac += wc[ci] * xv[ci]; }
      hab[(size_t)co * HW] = aa;
      hcb[(size_t)co * HW] = ac;
    }
    float* ab = att + (size_t)b * 32 * HW + sp;
    int n0 = slot * 2;
    for (int n = n0; n < n0 + 2; n++) {
      float a2 = b211[n];
      const float* w2 = w211 + n * 48;
      #pragma unroll
      for (int ci = 0; ci < 48; ci++) a2 += w2[ci] * xv[ci];
      ab[(size_t)n * HW] = a2;
    }
  } else if (blk < 2546) {
    // ---- prep ----
    int blk2 = blk - 2144;
    if (blk2 < 384) {
      int e = blk2 * 256 + tid;                    // < 98304
      int k = e & 31, nc = (e >> 5) & 63, g = e >> 11;
      int n = nc >> 1, i = nc & 1;
      int q = k >> 3, j2 = k & 7;
      float v = 0.f;
      int jj = -1;
      if (q == 0)      { if (j2 < 5) jj = j2; }
      else if (q == 1) { if (j2 < 5) jj = 9 + j2; }
      else if (q == 2) { if (j2 < 4) jj = 5 + j2; }
      else             { if (j2 < 4) jj = 14 + j2; else if (j2 == 4) v = kbb[n * 96 + 2 * g + i]; }
      if (jj >= 0) v = kbw[n * 1728 + g * 36 + i * 18 + jj];
      kwA[e] = bf16r(v);
    } else {
      int e = (blk2 - 384) * 256 + tid;            // < 4608
      if (e < 4608) {
        float w = wproj[e];
        unsigned short h = bf16r(w);
        wp[e] = h;
        float hif = __uint_as_float((unsigned)h << 16);
        wp[4608 + e] = bf16r(w - hif);
      }
    }
  } else {
    // ---- gate ----
    int idx = (blk - 2546) * 256 + tid;            // < B*12*HW = 393216
    int sp = idx & (HW - 1);
    int bi = idx >> 14;                            // b*12+i
    int i = bi % 12, b = bi / 12;
    int r = sp >> 7, c = sp & 127;
    const float* xb = x + (size_t)b * 48 * HW;
    float t[2];
    #pragma unroll
    for (int half = 0; half < 2; half++) {
      int o = i + half * 12;
      float acc = bc2a[o];
      #pragma unroll
      for (int ic = 0; ic < 2; ic++) {
        const float* xc = xb + (size_t)(2 * o + ic) * HW;
        const float* wo = wc2a + o * 18 + ic * 9;
        #pragma unroll
        for (int t9 = 0; t9 < 9; t9++) {
          int rr = r + t9 / 3 - 1, cc = c + t9 % 3 - 1;
          float v = (((unsigned)rr < 128u) && ((unsigned)cc < 128u)) ? xc[rr * Wd + cc] : 0.f;
          acc += wo[t9] * v;
        }
      }
      t[half] = acc;
    }
    m[idx] = t[0] * t[1];
  }
}

// ================= LAUNCH 2: dw (inline sca) | att2 (block ranges) ===========
// [0,3072): dw 4-px strips  -> x1g, uf
// [3072,5120): att2 in-place -> att
__global__ void k_combo2(
    const float* __restrict__ ha, const float* __restrict__ hc,
    const float* __restrict__ wdwa, const float* __restrict__ bdwa,
    const float* __restrict__ wdwc, const float* __restrict__ bdwc,
    const float* __restrict__ wsca, const float* __restrict__ bsca,
    const float* __restrict__ xmean,
    const float* __restrict__ m,
    const float* __restrict__ wc2b, const float* __restrict__ bc2b,
    const float* __restrict__ attg,
    float* __restrict__ x1g, float* __restrict__ uf, float* __restrict__ att) {
  int blk = blockIdx.x;
  int tid = threadIdx.x;
  if (blk < 3072) {
    // ---- dw, 4-px column strips; sca computed per block from xmean ----
    int idx = blk * 256 + tid;                     // < B*96*HW/4 = 786432
    int sp4 = idx & 4095;
    int bc = idx >> 12;                            // block-uniform
    int ch = bc % 96, bq = bc / 96;
    __shared__ float scs;
    if (tid == 0) {
      float a = bsca[ch];
      for (int ci = 0; ci < 48; ci++) a += wsca[ch * 48 + ci] * xmean[bq * 48 + ci];
      scs = a;
    }
    __syncthreads();
    int sp = sp4 * 4;
    int r = sp >> 7, c = sp & 127;                 // c in {0,4,...,124}
    const float* pa = ha + (size_t)bc * HW;
    const float* pc = hc + (size_t)bc * HW;
    bool cm = (c > 0), cp = (c < 124);
    float aa0 = bdwa[ch], aa1 = aa0, aa2 = aa0, aa3 = aa0;
    float gc0 = bdwc[ch], gc1 = gc0, gc2 = gc0, gc3 = gc0;
    #pragma unroll
    for (int ri = 0; ri < 3; ri++) {
      int rr = r + ri - 1;
      bool okr = ((unsigned)rr < 128u);
      const float* ra = pa + rr * Wd + c;
      const float* rc = pc + rr * Wd + c;
      float4 fa = okr ? *(const float4*)ra : make_float4(0.f, 0.f, 0.f, 0.f);
      float4 fc = okr ? *(const float4*)rc : make_float4(0.f, 0.f, 0.f, 0.f);
      float la = (okr && cm) ? ra[-1] : 0.f;
      float lc = (okr && cm) ? rc[-1] : 0.f;
      float ua = (okr && cp) ? ra[4] : 0.f;
      float uc = (okr && cp) ? rc[4] : 0.f;
      float wa0 = wdwa[ch * 9 + ri * 3], wa1 = wdwa[ch * 9 + ri * 3 + 1], wa2 = wdwa[ch * 9 + ri * 3 + 2];
      float wc0 = wdwc[ch * 9 + ri * 3], wc1 = wdwc[ch * 9 + ri * 3 + 1], wc2 = wdwc[ch * 9 + ri * 3 + 2];
      aa0 += wa0 * la   + wa1 * fa.x + wa2 * fa.y;
      aa1 += wa0 * fa.x + wa1 * fa.y + wa2 * fa.z;
      aa2 += wa0 * fa.y + wa1 * fa.z + wa2 * fa.w;
      aa3 += wa0 * fa.z + wa1 * fa.w + wa2 * ua;
      gc0 += wc0 * lc   + wc1 * fc.x + wc2 * fc.y;
      gc1 += wc0 * fc.x + wc1 * fc.y + wc2 * fc.z;
      gc2 += wc0 * fc.y + wc1 * fc.z + wc2 * fc.w;
      gc3 += wc0 * fc.z + wc1 * fc.w + wc2 * uc;
    }
    float sc = scs;
    const float k = 0.70710678118654752440f;
    float4 xg;
    xg.x = aa0 * 0.5f * (1.f + erff(aa0 * k)) * sc;
    xg.y = aa1 * 0.5f * (1.f + erff(aa1 * k)) * sc;
    xg.z = aa2 * 0.5f * (1.f + erff(aa2 * k)) * sc;
    xg.w = aa3 * 0.5f * (1.f + erff(aa3 * k)) * sc;
    *(float4*)(x1g + (size_t)bc * HW + sp) = xg;
    *(float4*)(uf + (size_t)bc * HW + sp) = make_float4(gc0, gc1, gc2, gc3);
  } else {
    // ---- att2 (flattened (512,4)): att += 1x1(m)*gamma, in place ----
    int bid2 = blk - 3072;
    int bx = bid2 & 511, quad = bid2 >> 9;
    int lane = tid & 63;
    int wv = __builtin_amdgcn_readfirstlane((int)(tid >> 6));
    int slot = __builtin_amdgcn_readfirstlane(quad * 4 + wv);
    int p = bx * 64 + lane;
    int b = p >> 14, sp = p & (HW - 1);
    float mv[12];
    const float* mb = m + (size_t)b * 12 * HW + sp;
    #pragma unroll
    for (int i = 0; i < 12; i++) mv[i] = mb[(size_t)i * HW];
    float* ab = att + (size_t)b * 32 * HW + sp;
    int n0 = slot * 2;
    for (int n = n0; n < n0 + 2; n++) {
      float a1 = bc2b[n];
      #pragma unroll
      for (int i = 0; i < 12; i++) a1 += wc2b[n * 12 + i] * mv[i];
      float* ap = ab + (size_t)n * HW;
      *ap = a1 * attg[n] + *ap;
    }
  }
}

// ---------------- K6: fused kba via MFMA (4 groups/block) ----------
// grid (512,12) x 256. Wave wv owns px [wv*16,+16); block covers 4 groups gq*4..+3.
__global__ __launch_bounds__(256) void k_kba(
    const float* __restrict__ uf, const float* __restrict__ x1g,
    const float* __restrict__ att, const unsigned short* __restrict__ kwA,
    const float* __restrict__ ga1, unsigned int* __restrict__ y2) {
  __shared__ __align__(16) short kwS[4 * 2048];    // 16 KB
  int tid = threadIdx.x;
  int lane = tid & 63;
  int wv = tid >> 6;
  int lo = lane & 15, hi = lane >> 4;
  int bid = blockIdx.x;                            // 0..511
  int b = bid >> 8;
  int sp = ((bid & 255) << 6) + wv * 16 + lo;      // this lane's pixel
  int r = sp >> 7, c = sp & 127;
  int g0 = blockIdx.y * 4;

  {
    const short8* src = (const short8*)(kwA + g0 * 2048);
    short8* dst = (short8*)kwS;
    #pragma unroll
    for (int i = 0; i < 4; i++) dst[tid + 256 * i] = src[tid + 256 * i];
  }

  const float* ufb  = uf  + (size_t)b * 96 * HW;
  const float* x1gb = x1g + (size_t)b * 96 * HW;
  const float* attb = att + (size_t)b * 32 * HW;
  unsigned int* y2b = y2 + (size_t)b * 48 * HW;

  float attv[8];
  #pragma unroll
  for (int mt = 0; mt < 4; mt++)
    #pragma unroll
    for (int q = 0; q < 2; q++)
      attv[mt * 2 + q] = attb[(size_t)(8 * mt + 2 * hi + q) * HW + sp];

  const float* pj[5];
  bool ok[5];
  float dv[5];
  #pragma unroll
  for (int j2 = 0; j2 < 5; j2++) {
    int jj = (hi == 0) ? j2 : (hi == 1) ? 9 + j2 : (hi == 2) ? 5 + j2 : 14 + j2;
    bool real = (hi < 2) || (j2 < 4);
    if (real) {
      int ch = jj / 9, tap = jj % 9;
      int rr = r + tap / 3 - 1, cc = c + tap % 3 - 1;
      bool inb = ((unsigned)rr < 128u) && ((unsigned)cc < 128u);
      ok[j2] = inb;
      dv[j2] = 0.f;
      pj[j2] = ufb + (size_t)(2 * g0 + ch) * HW + (inb ? rr * Wd + cc : 0);
    } else {
      ok[j2] = false;
      dv[j2] = (hi == 3) ? 1.f : 0.f;              // bias slot (q3, j2==4)
      pj[j2] = ufb;
    }
  }

  float vT[4][5];
  #pragma unroll
  for (int gi = 0; gi < 4; gi++)
    #pragma unroll
    for (int j2 = 0; j2 < 5; j2++)
      vT[gi][j2] = ok[j2] ? pj[j2][(size_t)(2 * gi) * HW] : dv[j2];
  float x1v[8];
  #pragma unroll
  for (int k = 0; k < 8; k++)
    x1v[k] = x1gb[(size_t)(2 * g0 + k) * HW + sp];

  __syncthreads();

  #pragma unroll
  for (int gp = 0; gp < 2; gp++) {
    int g = g0 + 2 * gp;
    float* va = vT[2 * gp];
    float* vb = vT[2 * gp + 1];
    const short* kgA = kwS + (2 * gp) * 2048;
    const short* kgB = kgA + 2048;
    short8 afrA[4], afrB[4];
    #pragma unroll
    for (int mt = 0; mt < 4; mt++) {
      afrA[mt] = *(const short8*)(kgA + (16 * mt + lo) * 32 + hi * 8);
      afrB[mt] = *(const short8*)(kgB + (16 * mt + lo) * 32 + hi * 8);
    }
    union { unsigned u[4]; short8 s; } bfA, bfB;
    bfA.u[0] = cvt_pk_bf16(va[0], va[1]);
    bfA.u[1] = cvt_pk_bf16(va[2], va[3]);
    bfA.u[2] = cvt_pk_bf16(va[4], 0.f);
    bfA.u[3] = 0u;
    bfB.u[0] = cvt_pk_bf16(vb[0], vb[1]);
    bfB.u[1] = cvt_pk_bf16(vb[2], vb[3]);
    bfB.u[2] = cvt_pk_bf16(vb[4], 0.f);
    bfB.u[3] = 0u;
    f32x4 accA[4], accB[4];
    f32x4 zero = {0.f, 0.f, 0.f, 0.f};
    #pragma unroll
    for (int mt = 0; mt < 4; mt++)
      accA[mt] = __builtin_amdgcn_mfma_f32_16x16x32_bf16(afrA[mt], bfA.s, zero, 0, 0, 0);
    #pragma unroll
    for (int mt = 0; mt < 4; mt++)
      accB[mt] = __builtin_amdgcn_mfma_f32_16x16x32_bf16(afrB[mt], bfB.s, zero, 0, 0, 0);
    float sA0 = 0.f, sA1 = 0.f, sB0 = 0.f, sB1 = 0.f;
    #pragma unroll
    for (int mt = 0; mt < 4; mt++) {
      sA0 += attv[mt * 2 + 0] * accA[mt][0] + attv[mt * 2 + 1] * accA[mt][2];
      sA1 += attv[mt * 2 + 0] * accA[mt][1] + attv[mt * 2 + 1] * accA[mt][3];
    }
    sA0 += __shfl_xor(sA0, 16); sA0 += __shfl_xor(sA0, 32);
    sA1 += __shfl_xor(sA1, 16); sA1 += __shfl_xor(sA1, 32);
    float cenA = __shfl_xor(va[4], 16);
    #pragma unroll
    for (int mt = 0; mt < 4; mt++) {
      sB0 += attv[mt * 2 + 0] * accB[mt][0] + attv[mt * 2 + 1] * accB[mt][2];
      sB1 += attv[mt * 2 + 0] * accB[mt][1] + attv[mt * 2 + 1] * accB[mt][3];
    }
    sB0 += __shfl_xor(sB0, 16); sB0 += __shfl_xor(sB0, 32);
    sB1 += __shfl_xor(sB1, 16); sB1 += __shfl_xor(sB1, 32);
    float cenB = __shfl_xor(vb[4], 16);
    if (hi == 0) {
      int c0 = 2 * g;
      float xa0 = sA0 * ga1[c0]     + va[4];
      float xa1 = sA1 * ga1[c0 + 1] + cenA;
      float ya0 = x1v[4 * gp]     * xa0;
      float ya1 = x1v[4 * gp + 1] * xa1;
      y2b[(size_t)g * HW + sp] = cvt_pk_bf16(ya0, ya1);
      float xb0 = sB0 * ga1[c0 + 2] + vb[4];
      float xb1 = sB1 * ga1[c0 + 3] + cenB;
      float yb0 = x1v[4 * gp + 2] * xb0;
      float yb1 = x1v[4 * gp + 3] * xb1;
      y2b[(size_t)(g + 1) * HW + sp] = cvt_pk_bf16(yb0, yb1);
    }
  }
}

// ---------------- K7: project_out 96->48 via MFMA (W = bf16 hi + bf16 lo) -------
__global__ void k_proj(const unsigned int* __restrict__ y2, const unsigned short* __restrict__ wp,
                       const float* __restrict__ bproj, float* __restrict__ out) {
  int tid = threadIdx.x;
  int lane = tid & 63;
  int wv = tid >> 6;
  int lo = lane & 15, hi = lane >> 4;
  int p0 = blockIdx.x * 64 + wv * 16;
  int b = p0 >> 14;
  int sp = (p0 & (HW - 1)) + lo;
  const unsigned int* yb = y2 + (size_t)b * 48 * HW + sp;
  union { unsigned u[4]; short8 s; } bf[3];
  #pragma unroll
  for (int ks = 0; ks < 3; ks++)
    #pragma unroll
    for (int q = 0; q < 4; q++)
      bf[ks].u[q] = yb[(size_t)(ks * 16 + hi * 4 + q) * HW];
  f32x4 acc[3];
  #pragma unroll
  for (int t = 0; t < 3; t++)
    #pragma unroll
    for (int r = 0; r < 4; r++)
      acc[t][r] = bproj[16 * t + 4 * hi + r];
  #pragma unroll
  for (int t = 0; t < 3; t++) {
    #pragma unroll
    for (int ks = 0; ks < 3; ks++) {
      short8 ah = *(const short8*)(wp + (16 * t + lo) * 96 + ks * 32 + hi * 8);
      acc[t] = __builtin_amdgcn_mfma_f32_16x16x32_bf16(ah, bf[ks].s, acc[t], 0, 0, 0);
      short8 al = *(const short8*)(wp + 4608 + (16 * t + lo) * 96 + ks * 32 + hi * 8);
      acc[t] = __builtin_amdgcn_mfma_f32_16x16x32_bf16(al, bf[ks].s, acc[t], 0, 0, 0);
    }
  }
  float* ob = out + (size_t)b * 48 * HW + sp;
  #pragma unroll
  for (int t = 0; t < 3; t++)
    #pragma unroll
    for (int r = 0; r < 4; r++)
      ob[(size_t)(16 * t + 4 * hi + r) * HW] = acc[t][r];
}

extern "C" void kernel_launch(void* const* d_in, const int* in_sizes, int n_in,
                              void* d_out, int out_size, void* d_ws, size_t ws_size,
                              hipStream_t stream) {
  const float* x    = (const float*)d_in[0];
  const float* w1a  = (const float*)d_in[1];
  const float* b1a  = (const float*)d_in[2];
  const float* wdwa = (const float*)d_in[3];
  const float* bdwa = (const float*)d_in[4];
  const float* w1c  = (const float*)d_in[5];
  const float* b1c  = (const float*)d_in[6];
  const float* wdwc = (const float*)d_in[7];
  const float* bdwc = (const float*)d_in[8];
  const float* wsca = (const float*)d_in[9];
  const float* bsca = (const float*)d_in[10];
  const float* wc2a = (const float*)d_in[11];
  const float* bc2a = (const float*)d_in[12];
  const float* wc2b = (const float*)d_in[13];
  const float* bc2b = (const float*)d_in[14];
  const float* w211 = (const float*)d_in[15];
  const float* b211 = (const float*)d_in[16];
  const float* wproj= (const float*)d_in[17];
  const float* bproj= (const float*)d_in[18];
  const float* kbw  = (const float*)d_in[19];
  const float* kbb  = (const float*)d_in[20];
  const float* attg = (const float*)d_in[21];
  const float* ga1  = (const float*)d_in[22];
  float* out = (float*)d_out;

  float* ws    = (float*)d_ws;
  float* xmean = ws;                 // 96
  float* ha    = ws + 288;           // 3145728 (later: y2)
  float* hc    = ha + 3145728;       // 3145728 (also: kwA + wp region)
  float* x1g   = hc + 3145728;       // 3145728
  float* uf    = x1g + 3145728;      // 3145728
  float* att   = uf + 3145728;       // 1048576
  float* m     = att + 1048576;      // 393216 (own region; live L1->L2)
  unsigned int* y2 = (unsigned int*)ha;           // y2 lifetime [kba, proj]
  unsigned short* kwA = (unsigned short*)hc;      // hc dead after combo2's dw
  unsigned short* wp  = kwA + 98304;              // wproj hi/lo bf16 (9216 u16)
  // NOTE: kwA/wp written in launch1 while hc is still live — they alias hc's
  // region, which pw1 ALSO writes in launch1!  -> place kwA AFTER m instead.
  kwA = (unsigned short*)(m + 393216);            // 98304 u16
  wp  = kwA + 98304;                              // 9216 u16

  k_combo1<<<4082, 256, 0, stream>>>(x, w1a, b1a, w1c, b1c, w211, b211,
                                     kbw, kbb, wproj, wc2a, bc2a,
                                     xmean, ha, hc, att, kwA, wp, m);
  k_combo2<<<5120, 256, 0, stream>>>(ha, hc, wdwa, bdwa, wdwc, bdwc,
                                     wsca, bsca, xmean, m, wc2b, bc2b, attg,
                                     x1g, uf, att);
  k_kba <<<dim3(512, 12), 256, 0, stream>>>(uf, x1g, att, kwA, ga1, y2);
  k_proj<<<512, 256, 0, stream>>>(y2, wp, bproj, out);
}